// Round 5
// baseline (169.094 us; speedup 1.0000x reference)
//
#include <hip/hip_runtime.h>
#include <math.h>

#define M_OBJ 4
#define N_PTS 3072
#define K_NN  10
#define NSLOT (M_OBJ - 1)
#define QPB   64            // queries per block (one per lane)
#define SEG   4             // reference segments (one per wave)
#define SEGN  (N_PTS / SEG) // 768 points per segment
#define B_CAND 12           // candidate buffer entries per lane
#define CSTR   13           // padded stride (bank spread)

typedef unsigned long long u64;

// T = inv(plane_T) @ est_T (3x4). plane_T is orthonormal-rigid: inv = [R^T|-R^T t].
__device__ inline void make_T(const float* __restrict__ E,
                              const float* __restrict__ P,
                              float T[3][4]) {
    float Pi[3][4];
#pragma unroll
    for (int i = 0; i < 3; ++i) {
#pragma unroll
        for (int j = 0; j < 3; ++j) Pi[i][j] = P[j * 4 + i];
        Pi[i][3] = -(P[0 * 4 + i] * P[3] + P[1 * 4 + i] * P[7] + P[2 * 4 + i] * P[11]);
    }
#pragma unroll
    for (int i = 0; i < 3; ++i) {
#pragma unroll
        for (int j = 0; j < 4; ++j) {
            float acc = (j == 3) ? Pi[i][3] : 0.0f;
#pragma unroll
            for (int kk = 0; kk < 3; ++kk) acc += Pi[i][kk] * E[kk * 4 + j];
            T[i][j] = acc;
        }
    }
}

// Keep bs[] ASCENDING in s (s = p.q - |p|^2/2; larger s == nearer).
// bs[0] = 10th-best (threshold), bs[9] = nearest. Compile-time indices only.
__device__ __forceinline__ void insert10(float s, int id, float bs[K_NN], int bi[K_NN]) {
    bs[0] = s; bi[0] = id;
#pragma unroll
    for (int t = 0; t < K_NN - 1; ++t) {
        if (bs[t] > bs[t + 1]) {
            float a = bs[t]; bs[t] = bs[t + 1]; bs[t + 1] = a;
            int   b = bi[t]; bi[t] = bi[t + 1]; bi[t + 1] = b;
        }
    }
}

__device__ __forceinline__ void drain(u64* cand, int tid, int& c,
                                      float bs[K_NN], int bi[K_NN]) {
    for (int i = 0; i < c; ++i) {          // per-lane count, exec-masked loop
        u64 e = cand[tid * CSTR + i];
        float s = __uint_as_float((unsigned)(e >> 32));
        if (s > bs[0]) insert10(s, (int)(e & 0xffffffffu), bs, bi);
    }
    c = 0;
}

__global__ __launch_bounds__(256, 2) void pair_kernel(
        const float* __restrict__ points,   // [M][N][6]
        const float* __restrict__ estT,     // [M][4][4]
        const float* __restrict__ planeT,   // [4][4]
        float* __restrict__ pair_sd) {      // [M][NSLOT][N]
    __shared__ float4 sref[N_PTS];          // 48 KiB: (x,y,z, |p|^2/2)
    __shared__ u64    cand[256 * CSTR];     // 26.6 KiB; reused for the merge

    const int pidx  = blockIdx.x;           // 0..11
    const int q     = pidx / NSLOT;
    const int rs    = pidx % NSLOT;
    const int r     = rs + (rs >= q ? 1 : 0);
    const int tid   = threadIdx.x;
    const int seg   = tid >> 6;             // wave id = segment
    const int qlane = tid & 63;

    float Tq[3][4], Tr[3][4];
    make_T(estT + q * 16, planeT, Tq);
    make_T(estT + r * 16, planeT, Tr);

    // Stage transformed ref points + half-squared-norm.
    for (int j = tid; j < N_PTS; j += 256) {
        const float* p = points + (size_t)(r * N_PTS + j) * 6;
        float2 xy = *(const float2*)p;
        float  z  = p[2];
        float px = Tr[0][0] * xy.x + Tr[0][1] * xy.y + Tr[0][2] * z + Tr[0][3];
        float py = Tr[1][0] * xy.x + Tr[1][1] * xy.y + Tr[1][2] * z + Tr[1][3];
        float pz = Tr[2][0] * xy.x + Tr[2][1] * xy.y + Tr[2][2] * z + Tr[2][3];
        float w  = 0.5f * (px * px + py * py + pz * pz);
        sref[j] = make_float4(px, py, pz, w);
    }
    __syncthreads();

    const int nq = blockIdx.y * QPB + qlane;
    const float* qp = points + (size_t)(q * N_PTS + nq) * 6;
    float2 qxy = *(const float2*)qp;
    float  qzz = qp[2];
    const float qx = Tq[0][0] * qxy.x + Tq[0][1] * qxy.y + Tq[0][2] * qzz + Tq[0][3];
    const float qy = Tq[1][0] * qxy.x + Tq[1][1] * qxy.y + Tq[1][2] * qzz + Tq[1][3];
    const float qz = Tq[2][0] * qxy.x + Tq[2][1] * qxy.y + Tq[2][2] * qzz + Tq[2][3];
    const float qq = qx * qx + qy * qy + qz * qz;   // sq = qq - 2s

    float bs[K_NN]; int bi[K_NN];
#pragma unroll
    for (int i = 0; i < K_NN; ++i) { bs[i] = -3.4e38f; bi[i] = 0; }
    int c = 0;

    // Branchless scan: 3 FMA/point; passing candidates pushed to LDS buffer.
    const int j0 = seg * SEGN;
    for (int jb = 0; jb < SEGN; jb += 8) {
        if (__any(c > B_CAND - 9)) drain(cand, tid, c, bs, bi);  // keeps c+8 <= 12
        const int jj = j0 + jb;
        float s8[8];
#pragma unroll
        for (int u = 0; u < 8; ++u) {
            float4 p = sref[jj + u];        // uniform addr -> LDS broadcast
            s8[u] = fmaf(p.x, qx, fmaf(p.y, qy, fmaf(p.z, qz, -p.w)));
        }
        float m01 = fmaxf(s8[0], s8[1]), m23 = fmaxf(s8[2], s8[3]);
        float m45 = fmaxf(s8[4], s8[5]), m67 = fmaxf(s8[6], s8[7]);
        float mx  = fmaxf(fmaxf(m01, m23), fmaxf(m45, m67));
        if (__any(mx > bs[0])) {
#pragma unroll
            for (int u = 0; u < 8; ++u) {
                if (s8[u] > bs[0]) {        // stale-conservative threshold: safe
                    cand[tid * CSTR + c] =
                        ((u64)__float_as_uint(s8[u]) << 32) | (unsigned)(jj + u);
                    ++c;
                }
            }
        }
    }
    drain(cand, tid, c, bs, bi);

    // Cascade merge: w2,w3 dump; w0<-w2, w1<-w3; w1 dumps; w0<-w1.
    __syncthreads();
    if (seg >= 2) {
#pragma unroll
        for (int i = 0; i < K_NN; ++i)
            cand[tid * CSTR + i] = ((u64)__float_as_uint(bs[i]) << 32) | (unsigned)bi[i];
    }
    __syncthreads();
    if (seg < 2) {
        const int src = (tid + 128) * CSTR;   // w0 reads w2's region, w1 reads w3's
#pragma unroll
        for (int i = 0; i < K_NN; ++i) {
            u64 e = cand[src + i];
            float s = __uint_as_float((unsigned)(e >> 32));
            if (s > bs[0]) insert10(s, (int)(e & 0xffffffffu), bs, bi);
        }
    }
    __syncthreads();
    if (seg == 1) {
#pragma unroll
        for (int i = 0; i < K_NN; ++i)
            cand[tid * CSTR + i] = ((u64)__float_as_uint(bs[i]) << 32) | (unsigned)bi[i];
    }
    __syncthreads();
    if (seg == 0) {
        const int src = (64 + qlane) * CSTR;
#pragma unroll
        for (int i = 0; i < K_NN; ++i) {
            u64 e = cand[src + i];
            float s = __uint_as_float((unsigned)(e >> 32));
            if (s > bs[0]) insert10(s, (int)(e & 0xffffffffu), bs, bi);
        }

        // Inside/outside vote (unnormalized grad: sign-preserving).
        int votes = 0;
#pragma unroll
        for (int i = 0; i < K_NN; ++i) {
            int id = bi[i];
            float4 p = sref[id];
            float gx = p.x - qx, gy = p.y - qy, gz = p.z - qz;
            const float* np_ = points + (size_t)(r * N_PTS + id) * 6 + 3;
            votes += (np_[0] * gx + np_[1] * gy + np_[2] * gz > 0.0f) ? 1 : 0;
        }

        float sq = fmaxf(fmaf(-2.0f, bs[K_NN - 1], qq), 0.0f);
        float d0 = sqrtf(sq);
        float sd = (votes > 8) ? -d0 : d0;
        pair_sd[((size_t)q * NSLOT + rs) * N_PTS + nq] = sd;
    }
}

__global__ __launch_bounds__(256) void reduce_kernel(
        const float* __restrict__ points,
        const float* __restrict__ estT,
        const float* __restrict__ planeT,
        const float* __restrict__ pair_sd,
        float* __restrict__ out) {
    int i = blockIdx.x * blockDim.x + threadIdx.x;
    if (i >= M_OBJ * N_PTS) return;
    int m = i / N_PTS, n = i % N_PTS;

    float T[3][4];
    make_T(estT + m * 16, planeT, T);
    const float* p = points + (size_t)i * 6;
    float zpl = T[2][0] * p[0] + T[2][1] * p[1] + T[2][2] * p[2] + T[2][3];

    float sd = zpl;
#pragma unroll
    for (int rs = 0; rs < NSLOT; ++rs)
        sd = fminf(sd, pair_sd[((size_t)m * NSLOT + rs) * N_PTS + n]);

    out[i] = sd;
    out[M_OBJ * N_PTS + i] = (sd < -0.01f) ? 1.0f : 0.0f;
}

extern "C" void kernel_launch(void* const* d_in, const int* in_sizes, int n_in,
                              void* d_out, int out_size, void* d_ws, size_t ws_size,
                              hipStream_t stream) {
    const float* points = (const float*)d_in[0];   // [4][3072][6]
    const float* estT   = (const float*)d_in[1];   // [4][4][4]
    const float* planeT = (const float*)d_in[2];   // [4][4]

    float* pair_sd = (float*)d_ws;                 // [4][3][3072]

    dim3 gridB(M_OBJ * NSLOT, N_PTS / QPB);        // 12 x 48 = 576 blocks
    pair_kernel<<<gridB, 256, 0, stream>>>(points, estT, planeT, pair_sd);

    int total = M_OBJ * N_PTS;
    reduce_kernel<<<(total + 255) / 256, 256, 0, stream>>>(points, estT, planeT,
                                                           pair_sd, (float*)d_out);
}